// Round 9
// baseline (139.992 us; speedup 1.0000x reference)
//
#include <hip/hip_runtime.h>
#include <hip/hip_cooperative_groups.h>
#include <math.h>

// Problem geometry (fixed by the reference setup)
#define CH       48
#define DIM      64
#define SPATIAL  (DIM * DIM * DIM)   // 262144 per (b, c)
#define NB       2
#define VOL      (NB * SPATIAL)      // 524288 per scale volume
#define NS       3
#define CSLAB    (SPATIAL / 4)       // 65536 f4 per (b,c) slab
#define ZT_PLANE 4096                // (d,h) plane in f4 units, per (s,b,w4)

// Phase 1: 16 rows x 16 lanes; 512 blocks cover 8192 W-rows
#define ROWS     16
// Phase 2: block = (b, w4, d-tile of 4), halo +-3 ; 2*16*16 = 512 blocks
#define DT       4
#define DTH      (DT + 6)
#define NITEM    (NS * DTH * DIM)    // 1920 tile entries

typedef float f4 __attribute__((ext_vector_type(4)));

namespace cgx = cooperative_groups;

// -------------------------------------------------------------------------
// Single cooperative kernel, 512 blocks x 256 threads (2 blocks/CU — 2x
// occupancy margin, so cooperative residency check cannot fail).
// Phase 1: channel mix + W box-sum -> zT[s][b][w4][d][h] (R4's kA body).
// grid.sync().  Phase 2: H box-sum + D box-sum + 1/k^3 + cross-scale sum
// + bias + sigmoid -> out (R6's kB body).  One 30 KB LDS arena, reused.
// -------------------------------------------------------------------------
__global__ __launch_bounds__(256, 2) void fused(
        const float* __restrict__ x,
        const float* __restrict__ fw,
        const float* __restrict__ fb,
        float* __restrict__ out,
        float* __restrict__ zt) {
    __shared__ __align__(16) char smem[NITEM * 16];     // 30720 B
    const int tid = threadIdx.x;

    // ---------------- Phase 1: channel mix + W pool ----------------
    {
        float* sw = (float*)smem;                        // [144]
        f4 (*t1)[ROWS][16] = (f4(*)[ROWS][16])(smem + 576);  // [NS][16][16]
        if (tid < NS * CH) sw[tid] = fw[tid];
        __syncthreads();

        const int lw  = tid & 15;                // f4 index along W
        const int lr  = tid >> 4;                // row in block, 0..15
        const int row = blockIdx.x * ROWS + lr;  // b*4096 + d*64 + h
        const int b   = row >> 12;
        const int dh  = row & 4095;              // d*64 + h

        const f4* xp = (const f4*)x
            + (size_t)b * CH * CSLAB + (size_t)dh * 16 + lw;

        f4 a0 = {0,0,0,0}, a1 = {0,0,0,0}, a2 = {0,0,0,0};
        #pragma unroll 16
        for (int c = 0; c < CH; ++c) {
            f4 v = xp[(size_t)c * CSLAB];
            a0 += sw[c] * v;
            a1 += sw[CH + c] * v;
            a2 += sw[2 * CH + c] * v;
        }
        t1[0][lr][lw] = a0;
        t1[1][lr][lw] = a1;
        t1[2][lr][lw] = a2;
        __syncthreads();

        const f4 zero = {0,0,0,0};
        #pragma unroll
        for (int s = 0; s < NS; ++s) {
            // 12-float window; zero past row ends == reference zero padding
            // (count_include_pad).
            f4 m1 = (lw > 0)  ? t1[s][lr][lw - 1] : zero;
            f4 m0 = t1[s][lr][lw];
            f4 p1 = (lw < 15) ? t1[s][lr][lw + 1] : zero;
            float f[12] = {m1.x, m1.y, m1.z, m1.w,
                           m0.x, m0.y, m0.z, m0.w,
                           p1.x, p1.y, p1.z, p1.w};
            const int p = s + 1;
            f4 r;
            #pragma unroll
            for (int j = 0; j < 4; ++j) {
                float acc = 0.f;
                #pragma unroll
                for (int i = -3; i <= 3; ++i)
                    if (i >= -p && i <= p) acc += f[4 + j + i];
                r[j] = acc;
            }
            // transposed store: zT[s][b][w4][d][h]
            ((f4*)zt)[((size_t)(s * NB + b) * 16 + lw) * ZT_PLANE + dh] = r;
        }
    }

    // Make zt visible device-wide (cross-XCD), then grid barrier.
    __threadfence();
    cgx::this_grid().sync();

    // ---------------- Phase 2: H pool + D pool + sigmoid ----------------
    f4* tile = (f4*)smem;                      // [NS][DTH][DIM] flattened
    const int bid = blockIdx.x;                // 2*16*16 = 512
    const int w4  = bid & 15;
    const int d0  = ((bid >> 4) & 15) * DT;
    const int b2  = bid >> 8;

    const f4* zt4 = (const f4*)zt;
    #pragma unroll
    for (int s = 0; s < NS; ++s) {
        const f4* src = zt4 + ((size_t)(s * NB + b2) * 16 + w4) * ZT_PLANE;
        #pragma unroll
        for (int t = 0; t < (DTH * DIM + 255) / 256; ++t) {
            int i = tid + t * 256;
            if (i < DTH * DIM) {
                int dd = i >> 6, h = i & 63;
                int gd = d0 - 3 + dd;
                f4 v = {0,0,0,0};
                if (gd >= 0 && gd < DIM) v = src[gd * 64 + h];
                tile[s * DTH * DIM + i] = v;   // zero halo == zero padding
            }
        }
    }
    __syncthreads();

    // H-pool in place (regs across a barrier; fixed-trip -> stays in VGPRs).
    f4 hacc[(NITEM + 255) / 256];
    #pragma unroll
    for (int t = 0; t < (NITEM + 255) / 256; ++t) {
        int j = tid + t * 256;
        f4 a = {0,0,0,0};
        if (j < NITEM) {
            int s   = j / (DTH * DIM);
            int rem = j - s * (DTH * DIM);
            int dd  = rem >> 6, h = rem & 63;
            int p   = s + 1;
            int lo  = h - p; if (lo < 0)  lo = 0;
            int hi  = h + p; if (hi > 63) hi = 63;
            for (int hh = lo; hh <= hi; ++hh)
                a += tile[(s * DTH + dd) * 64 + hh];
        }
        hacc[t] = a;
    }
    __syncthreads();
    #pragma unroll
    for (int t = 0; t < (NITEM + 255) / 256; ++t) {
        int j = tid + t * 256;
        if (j < NITEM) tile[j] = hacc[t];
    }
    __syncthreads();

    // D-pool + combine scales + bias + sigmoid -> final output (256 f4).
    {
        const float inv[NS] = {1.f / 27.f, 1.f / 125.f, 1.f / 343.f};
        const float bias = fb[0];
        const int ddp = tid >> 6, h = tid & 63;
        const int d   = d0 + ddp;
        f4 a2 = {bias, bias, bias, bias};
        #pragma unroll
        for (int s = 0; s < NS; ++s) {
            int p = s + 1;
            f4 a = {0,0,0,0};
            #pragma unroll
            for (int i = -3; i <= 3; ++i)      // halo rows already zero
                if (i >= -p && i <= p)
                    a += tile[(s * DTH + ddp + 3 + i) * 64 + h];
            a2 += a * inv[s];
        }
        f4 r;
        #pragma unroll
        for (int j = 0; j < 4; ++j) r[j] = 1.f / (1.f + __expf(-a2[j]));
        __builtin_nontemporal_store(r,
            &((f4*)out)[(size_t)b2 * (SPATIAL / 4) + (size_t)d * 1024 + h * 16 + w4]);
    }
}

// -------------------------------------------------------------------------
extern "C" void kernel_launch(void* const* d_in, const int* in_sizes, int n_in,
                              void* d_out, int out_size, void* d_ws, size_t ws_size,
                              hipStream_t stream) {
    const float* x  = (const float*)d_in[0];   // (2, 48, 64, 64, 64) f32
    const float* fw = (const float*)d_in[1];   // (1, 144) f32
    const float* fb = (const float*)d_in[2];   // (1,) f32
    float* out = (float*)d_out;                // (2, 1, 64, 64, 64) f32
    float* zt  = (float*)d_ws;                 // 3*VOL floats = 6.29 MB

    void* args[] = {(void*)&x, (void*)&fw, (void*)&fb, (void*)&out, (void*)&zt};
    hipLaunchCooperativeKernel((void*)fused, dim3(512), dim3(256),
                               args, 0, stream);
}

// Round 11
// 32.615 us; speedup vs baseline: 4.2923x; 4.2923x over previous
//
#include <hip/hip_runtime.h>
#include <math.h>

// Problem geometry (fixed by the reference setup)
#define CH       48
#define DIM      64
#define SPATIAL  (DIM * DIM * DIM)   // 262144 per (b, c)
#define NB       2
#define VOL      (NB * SPATIAL)      // 524288 per scale volume
#define NS       3
#define CSLAB    (SPATIAL / 4)       // 65536 f4 per (b,c) slab
#define ROWS     16                  // W-rows per block in kernel A
#define ZT_PLANE 4096                // (d,h) plane in f4 units, per (s,b,w4)
#define DT       8                   // d-tile in kernel B
#define DTH      (DT + 6)            // with +-3 halo
#define NITEM    (NS * DTH * DIM)    // 2688 tile entries

typedef float f4 __attribute__((ext_vector_type(4)));

// -------------------------------------------------------------------------
// A: channel reduction + W box-sum -> zT[s][b][w4][d][h] (transposed).
// R4's proven structure, but the W-pool epilogue uses intra-wave shuffles
// (16-lane segments hold one 64-float W row) instead of an LDS tile:
// no tile LDS, no extra __syncthreads.  x read once, nt, unroll 8.
// Grid: NB*4096 W-rows / ROWS = 512 blocks.
// -------------------------------------------------------------------------
__global__ __launch_bounds__(256) void kA(
        const float* __restrict__ x,
        const float* __restrict__ fw,
        float* __restrict__ zt) {
    __shared__ float sw[NS * CH];
    const int tid = threadIdx.x;
    if (tid < NS * CH) sw[tid] = fw[tid];
    __syncthreads();

    const int lw  = tid & 15;                // f4 index along W
    const int lr  = tid >> 4;                // row in block, 0..15
    const int row = blockIdx.x * ROWS + lr;  // b*4096 + d*64 + h
    const int b   = row >> 12;
    const int dh  = row & 4095;              // d*64 + h

    const f4* xp = (const f4*)x
        + (size_t)b * CH * CSLAB + (size_t)dh * 16 + lw;

    f4 a0 = {0,0,0,0}, a1 = {0,0,0,0}, a2 = {0,0,0,0};
    #pragma unroll 8
    for (int c = 0; c < CH; ++c) {
        f4 v = __builtin_nontemporal_load(&xp[(size_t)c * CSLAB]);
        a0 += sw[c] * v;
        a1 += sw[CH + c] * v;
        a2 += sw[2 * CH + c] * v;
    }

    f4 accs[3] = {a0, a1, a2};
    f4* zt4 = (f4*)zt;
    #pragma unroll
    for (int s = 0; s < NS; ++s) {
        f4 cur = accs[s];
        // Neighbor f4 components from adjacent lanes (same 16-lane segment).
        // Only m1.y/z/w and p1.x/y/z are ever used by the window sums.
        float f1  = __shfl_up(cur.y, 1, 16);    // m1.y
        float f2  = __shfl_up(cur.z, 1, 16);    // m1.z
        float f3  = __shfl_up(cur.w, 1, 16);    // m1.w
        float f8  = __shfl_down(cur.x, 1, 16);  // p1.x
        float f9  = __shfl_down(cur.y, 1, 16);  // p1.y
        float f10 = __shfl_down(cur.z, 1, 16);  // p1.z
        if (lw == 0)  { f1 = f2 = f3 = 0.f; }   // zero padding at row start
        if (lw == 15) { f8 = f9 = f10 = 0.f; }  // zero padding at row end
        float f[12] = {0.f, f1, f2, f3,
                       cur.x, cur.y, cur.z, cur.w,
                       f8, f9, f10, 0.f};
        const int p = s + 1;
        f4 r;
        #pragma unroll
        for (int j = 0; j < 4; ++j) {
            float acc = 0.f;
            #pragma unroll
            for (int i = -3; i <= 3; ++i)
                if (i >= -p && i <= p) acc += f[4 + j + i];
            r[j] = acc;
        }
        // transposed store: zT[s][b][w4][d][h]
        zt4[((size_t)(s * NB + b) * 16 + lw) * ZT_PLANE + dh] = r;
    }
}

// -------------------------------------------------------------------------
// B: fused H box-sum + D box-sum + 1/k^3 + cross-scale sum + bias + sigmoid.
// R4's proven version (DT=8, 256 blocks): loads zT tile (3 x 14 x 64 f4,
// 43 KB) fully contiguous, H-pools in place (regs across a barrier),
// D-pools from LDS, writes final output.
// -------------------------------------------------------------------------
__global__ __launch_bounds__(256) void kB(
        const float* __restrict__ zt,
        const float* __restrict__ fb,
        float* __restrict__ out) {
    __shared__ f4 tile[NS][DTH][DIM];        // 2688 f4 = 43 KB
    const int tid = threadIdx.x;
    const int bid = blockIdx.x;              // 2*16*8 = 256 blocks
    const int w4  = bid & 15;
    const int d0  = ((bid >> 4) & 7) * DT;
    const int b   = bid >> 7;

    const f4* zt4 = (const f4*)zt;
    #pragma unroll
    for (int s = 0; s < NS; ++s) {
        const f4* src = zt4 + ((size_t)(s * NB + b) * 16 + w4) * ZT_PLANE;
        #pragma unroll
        for (int t = 0; t < (DTH * DIM + 255) / 256; ++t) {
            int i = tid + t * 256;
            if (i < DTH * DIM) {
                int dd = i >> 6, h = i & 63;
                int gd = d0 - 3 + dd;
                f4 v = {0,0,0,0};
                if (gd >= 0 && gd < DIM) v = src[gd * 64 + h];
                tile[s][dd][h] = v;          // zero-filled halo == zero padding
            }
        }
    }
    __syncthreads();

    // H-pool in place: compute all windows into regs, barrier, write back.
    f4 acc[11];                              // fixed-trip -> stays in VGPRs
    #pragma unroll
    for (int t = 0; t < 11; ++t) {
        int j = tid + t * 256;
        f4 a = {0,0,0,0};
        if (j < NITEM) {
            int s   = j / (DTH * DIM);
            int rem = j - s * (DTH * DIM);
            int dd  = rem >> 6, h = rem & 63;
            int p   = s + 1;
            int lo  = h - p; if (lo < 0)  lo = 0;
            int hi  = h + p; if (hi > 63) hi = 63;
            for (int hh = lo; hh <= hi; ++hh) a += tile[s][dd][hh];
        }
        acc[t] = a;
    }
    __syncthreads();
    #pragma unroll
    for (int t = 0; t < 11; ++t) {
        int j = tid + t * 256;
        if (j < NITEM) {
            int s   = j / (DTH * DIM);
            int rem = j - s * (DTH * DIM);
            tile[s][rem >> 6][rem & 63] = acc[t];
        }
    }
    __syncthreads();

    // D-pool + combine scales + bias + sigmoid -> final output.
    const float inv[NS] = {1.f / 27.f, 1.f / 125.f, 1.f / 343.f};
    const float bias = fb[0];
    f4* out4 = (f4*)out;
    #pragma unroll
    for (int t = 0; t < DT * DIM / 256; ++t) {   // 2 iters
        int j   = tid + t * 256;
        int ddp = j >> 6, h = j & 63;
        int d   = d0 + ddp;
        f4 a2 = {bias, bias, bias, bias};
        #pragma unroll
        for (int s = 0; s < NS; ++s) {
            int p = s + 1;
            f4 a = {0,0,0,0};
            for (int i = -3; i <= 3; ++i)        // halo rows already zero
                if (i >= -p && i <= p) a += tile[s][ddp + 3 + i][h];
            a2 += a * inv[s];
        }
        f4 r;
        #pragma unroll
        for (int jj = 0; jj < 4; ++jj) r[jj] = 1.f / (1.f + __expf(-a2[jj]));
        __builtin_nontemporal_store(r,
            &out4[(size_t)b * (SPATIAL / 4) + (size_t)d * 1024 + h * 16 + w4]);
    }
}

// -------------------------------------------------------------------------
extern "C" void kernel_launch(void* const* d_in, const int* in_sizes, int n_in,
                              void* d_out, int out_size, void* d_ws, size_t ws_size,
                              hipStream_t stream) {
    const float* x  = (const float*)d_in[0];   // (2, 48, 64, 64, 64) f32
    const float* fw = (const float*)d_in[1];   // (1, 144) f32
    const float* fb = (const float*)d_in[2];   // (1,) f32
    float* out = (float*)d_out;                // (2, 1, 64, 64, 64) f32

    float* zt = (float*)d_ws;                  // 3*VOL floats = 6.29 MB

    // A: channel mix + W box-sum -> zT (transposed), 512 blocks
    // (NB*DIM*DIM W-rows ... total rows = NB*4096 = 8192; /ROWS = 512)
    kA<<<(NB * DIM * DIM * DIM / DIM) / ROWS, 256, 0, stream>>>(x, fw, zt);
    // B: H-pool + D-pool + scale + bias + sigmoid -> out, 256 blocks
    kB<<<NB * 16 * (DIM / DT), 256, 0, stream>>>(zt, fb, out);
}